// Round 3
// baseline (716.786 us; speedup 1.0000x reference)
//
#include <hip/hip_runtime.h>
#include <hip/hip_bf16.h>

#define BB 8
#define CC 128
#define HH 128
#define WW 128
#define HW (HH*WW)
#define EE 4
#define EPSL 1e-6f

__device__ inline float b2f(unsigned short u){
  union { unsigned int i; float f; } v; v.i = ((unsigned int)u)<<16; return v.f;
}
__device__ inline unsigned short f2b(float f){
  union { float f; unsigned int i; } v; v.f = f;
  unsigned int x = v.i;
  return (unsigned short)((x + 0x7fffu + ((x>>16)&1u)) >> 16);
}

// ---------------- K1: LayerNorm over C (per pixel) + feat partial sums ----------
__global__ __launch_bounds__(256) void k_ln(
    const float* __restrict__ x, const float* __restrict__ gamma,
    const float* __restrict__ beta, unsigned short* __restrict__ xin,
    float* __restrict__ feat_sum) {
  int b = blockIdx.y;
  int p = blockIdx.x*256 + threadIdx.x;
  const float* xb = x + (size_t)b*CC*HW + p;
  float s=0.f, s2=0.f;
  for (int c=0;c<CC;c++){ float v = xb[(size_t)c*HW]; s+=v; s2+=v*v; }
  float mu = s*(1.f/CC);
  float var = s2*(1.f/CC) - mu*mu;
  float rs = rsqrtf(var + EPSL);
  __shared__ float lfeat[CC];
  for (int c=threadIdx.x;c<CC;c+=256) lfeat[c]=0.f;
  __syncthreads();
  int lane = threadIdx.x & 63;
  unsigned short* xo = xin + (size_t)b*CC*HW + p;
  for (int c=0;c<CC;c++){
    float v = (xb[(size_t)c*HW]-mu)*rs*gamma[c]+beta[c];
    xo[(size_t)c*HW] = f2b(v);
    float r = v;
    for (int o=32;o>0;o>>=1) r += __shfl_down(r, o);
    if (lane==0) atomicAdd(&lfeat[c], r);
  }
  __syncthreads();
  for (int c=threadIdx.x;c<CC;c+=256) atomicAdd(&feat_sum[b*CC+c], lfeat[c]);
}

// ---------------- K2: router (1 block) -----------------------------------------
__global__ __launch_bounds__(256) void k_router(
    const float* __restrict__ feat_sum, const float* __restrict__ prompt,
    const float* __restrict__ rw, const float* __restrict__ rb,
    const float* __restrict__ b2, const float* __restrict__ pw,
    const float* __restrict__ pb,
    int* __restrict__ eidx, float* __restrict__ wgt, float* __restrict__ bias_out) {
  __shared__ float logits[BB][EE];
  __shared__ float gate[BB][EE];
  __shared__ float cb[BB][CC];
  int t = threadIdx.x;
  if (t < BB*EE) {
    int b = t/EE, e = t%EE;
    float acc = rb[e];
    for (int c=0;c<CC;c++) acc += (feat_sum[b*CC+c]*(1.f/HW))*rw[c*EE+e];
    for (int c=0;c<CC;c++) acc += prompt[b*CC+c]*rw[(CC+c)*EE+e];
    logits[b][e]=acc;
  }
  __syncthreads();
  if (t < BB) {
    int b=t;
    float m=-1e30f;
    for(int e=0;e<EE;e++) m=fmaxf(m,logits[b][e]);
    float s=0.f, pr[EE];
    for(int e=0;e<EE;e++){ pr[e]=__expf(logits[b][e]-m); s+=pr[e]; }
    for(int e=0;e<EE;e++){ pr[e]/=s; gate[b][e]=0.f; }
    int i1=0; for(int e=1;e<EE;e++) if (pr[e]>pr[i1]) i1=e;
    int i2=-1; for(int e=0;e<EE;e++){ if(e==i1) continue; if(i2<0||pr[e]>pr[i2]) i2=e; }
    eidx[b*2]=i1; eidx[b*2+1]=i2;
    wgt[b*2]=pr[i1]; wgt[b*2+1]=pr[i2];
    gate[b][i1]=pr[i1]; gate[b][i2]=pr[i2];
  }
  __syncthreads();
  for (int i=t;i<BB*CC;i+=256){
    int b=i/CC, c=i%CC;
    float a=0.f;
    for(int e=0;e<EE;e++) a += gate[b][e]*b2[e*CC+c];
    cb[b][c]=a;
  }
  __syncthreads();
  for (int i=t;i<BB*CC;i+=256){
    int b=i/CC, o=i%CC;
    float a=pb[o];
    for (int c=0;c<CC;c++) a += pw[o*CC+c]*cb[b][c];
    bias_out[b*CC+o]=a;
  }
}

// ---------------- K3: w2p[e] = pw @ w2[e] (folded projection), bf16 -------------
__global__ __launch_bounds__(128) void k_prepw2(
    const float* __restrict__ pw, const float* __restrict__ w2,
    unsigned short* __restrict__ w2p){
  int eo = blockIdx.x; int e = eo/CC, o = eo%CC;
  int c = threadIdx.x;
  float a=0.f;
  for (int m=0;m<CC;m++) a += pw[o*CC+m]*w2[((size_t)e*CC+m)*CC+c];
  w2p[((size_t)e*CC+o)*CC+c] = f2b(a);
}

// ---------------- K4: GEMM1  t1 = w1[e] @ x_in[b] + b1[e] -----------------------
// block tile 128(o) x 128(p), 256 threads, 8x8 per thread
__global__ __launch_bounds__(256) void k_gemm1(
    const unsigned short* __restrict__ xin, const float* __restrict__ w1,
    const float* __restrict__ b1, const int* __restrict__ eidx,
    unsigned short* __restrict__ t1) {
  int bk = blockIdx.z;
  int b = bk>>1, k = bk&1;
  int e = eidx[b*2+k];
  int p0 = blockIdx.x*128;
  int tid = threadIdx.x;
  int tx = tid & 15, ty = tid >> 4;
  __shared__ float la[128][17];
  __shared__ float lb[16][128];
  float acc[8][8] = {};
  const float* w1e = w1 + (size_t)e*CC*CC;
  const unsigned short* xb = xin + (size_t)b*CC*HW;
  for (int c0=0;c0<CC;c0+=16){
    for (int i=0;i<8;i++){
      int flat = tid + i*256;
      int r = flat>>4, cc = flat&15;
      la[r][cc] = w1e[r*CC + c0+cc];
    }
    for (int i=0;i<8;i++){
      int flat = tid + i*256;
      int r = flat>>7, cc = flat&127;
      lb[r][cc] = b2f(xb[(size_t)(c0+r)*HW + p0+cc]);
    }
    __syncthreads();
    for (int kk=0;kk<16;kk++){
      float av[8], bv[8];
      for (int i=0;i<8;i++) av[i]=la[ty*8+i][kk];
      for (int j=0;j<8;j++) bv[j]=lb[kk][tx*8+j];
      for (int i=0;i<8;i++) for (int j=0;j<8;j++) acc[i][j] += av[i]*bv[j];
    }
    __syncthreads();
  }
  unsigned short* t1o = t1 + ((size_t)bk*CC)*HW;
  for (int i=0;i<8;i++){
    int o = ty*8+i;
    float bias = b1[e*CC+o];
    for (int j=0;j<8;j++){
      t1o[(size_t)o*HW + p0+tx*8+j] = f2b(acc[i][j]+bias);
    }
  }
}

// ---------------- K5: depthwise 3x3 + bias + exact GELU -------------------------
__global__ __launch_bounds__(256) void k_dw(
    const unsigned short* __restrict__ t1,
    const float* __restrict__ dw, const float* __restrict__ bdw,
    const int* __restrict__ eidx,
    unsigned short* __restrict__ t3) {
  int bk = blockIdx.z, b=bk>>1, k=bk&1;
  int e = eidx[b*2+k];
  int o = blockIdx.y;
  int p = blockIdx.x*256 + threadIdx.x;
  int h = p>>7, w = p&(WW-1);
  const unsigned short* src = t1 + ((size_t)bk*CC+o)*HW;
  const float* kd = dw + ((size_t)e*CC+o)*9;
  float acc = bdw[e*CC+o];
  #pragma unroll
  for (int dy=-1;dy<=1;dy++){
    int h2=h+dy; if (h2<0||h2>=HH) continue;
    #pragma unroll
    for (int dx=-1;dx<=1;dx++){
      int w2c=w+dx; if (w2c<0||w2c>=WW) continue;
      acc += kd[(dy+1)*3+(dx+1)] * b2f(src[h2*WW+w2c]);
    }
  }
  float g = 0.5f*acc*(1.f+erff(acc*0.70710678f));
  t3[((size_t)bk*CC+o)*HW + p] = f2b(g);
}

// ---------------- K6: GEMM2 (both experts, gate-weighted) + residual + bias -----
__global__ __launch_bounds__(256) void k_gemm2(
    const unsigned short* __restrict__ t3, const unsigned short* __restrict__ w2p,
    const int* __restrict__ eidx, const float* __restrict__ wgt,
    const float* __restrict__ bias_out, const float* __restrict__ x,
    float* __restrict__ out) {
  int b = blockIdx.z;
  int p0 = blockIdx.x*128;
  int tid=threadIdx.x, tx=tid&15, ty=tid>>4;
  __shared__ float la[128][17];
  __shared__ float lb[16][128];
  float acc[8][8]={};
  for (int k=0;k<2;k++){
    int e = eidx[b*2+k];
    float wv = wgt[b*2+k];
    const unsigned short* w2e = w2p + (size_t)e*CC*CC;
    const unsigned short* t3b = t3 + ((size_t)(b*2+k)*CC)*HW;
    for (int c0=0;c0<CC;c0+=16){
      for (int i=0;i<8;i++){
        int flat=tid+i*256, r=flat>>4, cc=flat&15;
        la[r][cc] = wv * b2f(w2e[r*CC+c0+cc]);
      }
      for (int i=0;i<8;i++){
        int flat=tid+i*256, r=flat>>7, cc=flat&127;
        lb[r][cc] = b2f(t3b[(size_t)(c0+r)*HW+p0+cc]);
      }
      __syncthreads();
      for (int kk=0;kk<16;kk++){
        float av[8],bv[8];
        for(int i=0;i<8;i++) av[i]=la[ty*8+i][kk];
        for(int j=0;j<8;j++) bv[j]=lb[kk][tx*8+j];
        for(int i=0;i<8;i++) for(int j=0;j<8;j++) acc[i][j]+=av[i]*bv[j];
      }
      __syncthreads();
    }
  }
  const float* xb = x + (size_t)b*CC*HW;
  float* ob = out + (size_t)b*CC*HW;
  for (int i=0;i<8;i++){
    int o=ty*8+i;
    float bo = bias_out[b*CC+o];
    for (int j=0;j<8;j++){
      size_t idx = (size_t)o*HW + p0+tx*8+j;
      ob[idx] = xb[idx] + acc[i][j] + bo;
    }
  }
}

extern "C" void kernel_launch(void* const* d_in, const int* in_sizes, int n_in,
                              void* d_out, int out_size, void* d_ws, size_t ws_size,
                              hipStream_t stream) {
  const float* x      = (const float*)d_in[0];
  const float* prompt = (const float*)d_in[1];
  const float* gamma  = (const float*)d_in[2];
  const float* beta   = (const float*)d_in[3];
  const float* rw     = (const float*)d_in[4];
  const float* rb     = (const float*)d_in[5];
  const float* w1     = (const float*)d_in[6];
  const float* b1     = (const float*)d_in[7];
  const float* dw     = (const float*)d_in[8];
  const float* bdw    = (const float*)d_in[9];
  const float* w2     = (const float*)d_in[10];
  const float* b2     = (const float*)d_in[11];
  const float* pw     = (const float*)d_in[12];
  const float* pb     = (const float*)d_in[13];
  float* out = (float*)d_out;

  char* base = (char*)d_ws;
  size_t off = 0;
  auto alloc = [&](size_t bytes)->void* {
    void* p = base + off;
    off = (off + bytes + 255) & ~(size_t)255;
    return p;
  };
  unsigned short* xin  = (unsigned short*)alloc((size_t)BB*CC*HW*2);       // 32 MiB
  unsigned short* t1   = (unsigned short*)alloc((size_t)BB*2*CC*HW*2);     // 64 MiB
  unsigned short* t3   = (unsigned short*)alloc((size_t)BB*2*CC*HW*2);     // 64 MiB
  unsigned short* w2p  = (unsigned short*)alloc((size_t)EE*CC*CC*2);
  float* feat_sum      = (float*)alloc(BB*CC*4);
  int*   eidx          = (int*)alloc(BB*2*4);
  float* wgt           = (float*)alloc(BB*2*4);
  float* bias_out      = (float*)alloc(BB*CC*4);

  hipMemsetAsync(feat_sum, 0, BB*CC*4, stream);

  k_ln<<<dim3(HW/256, BB), 256, 0, stream>>>(x, gamma, beta, xin, feat_sum);
  k_prepw2<<<dim3(EE*CC), 128, 0, stream>>>(pw, w2, w2p);
  k_router<<<dim3(1), 256, 0, stream>>>(feat_sum, prompt, rw, rb, b2, pw, pb,
                                        eidx, wgt, bias_out);
  k_gemm1<<<dim3(HW/128, 1, BB*2), 256, 0, stream>>>(xin, w1, b1, eidx, t1);
  k_dw<<<dim3(HW/256, CC, BB*2), 256, 0, stream>>>(t1, dw, bdw, eidx, t3);
  k_gemm2<<<dim3(HW/128, 1, BB), 256, 0, stream>>>(t3, w2p, eidx, wgt, bias_out,
                                                   x, out);
}